// Round 5
// baseline (222.186 us; speedup 1.0000x reference)
//
#include <hip/hip_runtime.h>
#include <stdint.h>

#define HH 56
#define WW 56
#define HW 3136
#define CC 128
#define BB 32
#define NPIX 100352        // B*H*W
#define NTOT 12845056      // B*C*H*W
#define EPSV 1e-5

struct alignas(16) U2 { unsigned long long lo, hi; };

// ---------------- K0: pack weights (sign bits along input channel) in TAP-MAJOR
// layout wbT[tap*128 + o]; also per-(tensor,o,tap) popcount stat and zero accumulators.
__global__ void k_pack_w(const float* __restrict__ w1, const float* __restrict__ w2,
                         U2* __restrict__ wbT1, U2* __restrict__ wbT2,
                         int* __restrict__ wpcg,
                         unsigned long long* __restrict__ sums1,
                         double* __restrict__ sums2) {
    int gtid = blockIdx.x * 256 + threadIdx.x;      // 2304 jobs
    if (gtid < 256) sums1[gtid] = 0ull;
    else if (gtid < 512) sums2[gtid - 256] = 0.0;
    int tensor = gtid / 1152, rem = gtid % 1152;
    int o = rem / 9, tap = rem % 9;
    const float* w = tensor ? w2 : w1;
    unsigned long long lo = 0, hi = 0;
    for (int i = 0; i < 64; ++i)
        if (w[(o * 128 + i) * 9 + tap] > 0.f) lo |= 1ull << i;
    for (int i = 64; i < 128; ++i)
        if (w[(o * 128 + i) * 9 + tap] > 0.f) hi |= 1ull << (i - 64);
    U2 u; u.lo = lo; u.hi = hi;
    (tensor ? wbT2 : wbT1)[tap * 128 + o] = u;
    wpcg[gtid] = 128 - 2 * (int)(__popcll(lo) + __popcll(hi));
}

// ---------------- K0b: border-correction tables ctab[o*9 + pattern]
__global__ void k_corr(const int* __restrict__ wpcg,
                       int* __restrict__ ctab1, int* __restrict__ ctab2) {
    int gtid = blockIdx.x * 256 + threadIdx.x;      // 2304 jobs
    int tensor = gtid / 1152, rem = gtid % 1152;
    int o = rem / 9, p = rem % 9;
    int ph = p / 3, pw = p % 3;
    int c = 0;
#pragma unroll
    for (int t = 0; t < 9; ++t) {
        int kh = t / 3, kw = t % 3;
        bool inval = (ph == 1 && kh == 0) || (ph == 2 && kh == 2) ||
                     (pw == 1 && kw == 0) || (pw == 2 && kw == 2);
        if (inval) c += wpcg[tensor * 1152 + o * 9 + t];
    }
    (tensor ? ctab2 : ctab1)[o * 9 + p] = c;
}

// ---------------- K1: pack x sign bits, fully coalesced.
__global__ void k_pack_x(const float* __restrict__ x, U2* __restrict__ xb) {
    __shared__ unsigned sm[64][5];                  // +1 pad: conflict-free
    int tid = threadIdx.x;
    int cq = tid >> 6, pl = tid & 63;
    int P0 = blockIdx.x * 64;                       // 64 | HW so b uniform per block
    int pix = P0 + pl;
    int b = pix / HW, r = pix % HW;
    const float* base = x + ((size_t)(b * CC + cq * 32)) * HW + r;
    unsigned m = 0;
#pragma unroll
    for (int c = 0; c < 32; ++c)
        if (base[(size_t)c * HW] > 0.f) m |= 1u << c;
    sm[pl][cq] = m;
    __syncthreads();
    if (tid < 64) {
        U2 u;
        u.lo = (unsigned long long)sm[tid][0] | ((unsigned long long)sm[tid][1] << 32);
        u.hi = (unsigned long long)sm[tid][2] | ((unsigned long long)sm[tid][3] << 32);
        xb[P0 + tid] = u;
    }
}

// ---------------- K2/K4: binary conv 3x3, 4 px/thread, 8 o-channels/block.
// TAP-OUTER structure: per tap, load 4 neighbor words (16 VGPR) and accumulate
// into S[8][4] (32 VGPR) with scalar-path weights — peak live ~60 regs, no spill.
template <int RESID>
__global__ __launch_bounds__(256)
void k_conv8(const U2* __restrict__ xb, const U2* __restrict__ wbT,
             const int* __restrict__ ctab,
             short* __restrict__ yout,
             const float* __restrict__ resid, float* __restrict__ tout,
             unsigned long long* __restrict__ isums, double* __restrict__ dsums) {
    __shared__ double sW[4][8], ssW[4][8];
    __shared__ long long iW[4][8], iiW[4][8];
    int tid = threadIdx.x;
    int wid = tid >> 6, lane = tid & 63;
    int o0 = blockIdx.y * 8;
    int g = blockIdx.x * 256 + tid;                 // 4-pixel group
    int pix0 = g * 4;
    int b = pix0 / HW, r = pix0 % HW;
    int h = r / WW, w0 = r % WW;                    // groups never cross rows

    int S[8][4];
#pragma unroll
    for (int oo = 0; oo < 8; ++oo)
#pragma unroll
        for (int j = 0; j < 4; ++j) S[oo][j] = 0;

    const U2* xbb = xb + (size_t)b * HW;
#pragma unroll
    for (int t = 0; t < 9; ++t) {
        int kh = t / 3, kw = t % 3;
        int row = h - 1 + kh;
        bool rv = (unsigned)row < HH;
        uint4 A0 = make_uint4(0,0,0,0), A1 = A0, A2 = A0, A3 = A0;
        {
            int col = w0 - 1 + kw;
            const U2* rp = xbb + row * WW;
            if (rv && (unsigned)(col + 0) < WW) A0 = *reinterpret_cast<const uint4*>(rp + col + 0);
            if (rv && (unsigned)(col + 1) < WW) A1 = *reinterpret_cast<const uint4*>(rp + col + 1);
            if (rv && (unsigned)(col + 2) < WW) A2 = *reinterpret_cast<const uint4*>(rp + col + 2);
            if (rv && (unsigned)(col + 3) < WW) A3 = *reinterpret_cast<const uint4*>(rp + col + 3);
        }
        const uint4* wq = reinterpret_cast<const uint4*>(wbT + (size_t)t * 128 + o0);
#pragma unroll
        for (int oo = 0; oo < 8; ++oo) {
            uint4 wv = wq[oo];                       // block-uniform -> s_load
            S[oo][0] += __popc(A0.x ^ wv.x) + __popc(A0.y ^ wv.y)
                      + __popc(A0.z ^ wv.z) + __popc(A0.w ^ wv.w);
            S[oo][1] += __popc(A1.x ^ wv.x) + __popc(A1.y ^ wv.y)
                      + __popc(A1.z ^ wv.z) + __popc(A1.w ^ wv.w);
            S[oo][2] += __popc(A2.x ^ wv.x) + __popc(A2.y ^ wv.y)
                      + __popc(A2.z ^ wv.z) + __popc(A2.w ^ wv.w);
            S[oo][3] += __popc(A3.x ^ wv.x) + __popc(A3.y ^ wv.y)
                      + __popc(A3.z ^ wv.z) + __popc(A3.w ^ wv.w);
        }
    }

    int ph = (h == 0) ? 1 : ((h == HH - 1) ? 2 : 0);
    int pbase = ph * 3;
    int jspec = (w0 == 0) ? 0 : ((w0 == WW - 4) ? 3 : -1);
    int pspec = pbase + ((w0 == 0) ? 1 : 2);        // always a valid index

    size_t obase = (size_t)(b * CC + o0) * HW + r;
#pragma unroll
    for (int oo = 0; oo < 8; ++oo) {
        int o = o0 + oo;
        int ci = ctab[o * 9 + pbase];               // 0 for interior
        int cs = ctab[o * 9 + pspec];
        int c0 = (jspec == 0) ? cs : ci;
        int c3 = (jspec == 3) ? cs : ci;
        int y0 = 1152 - 2 * S[oo][0] - c0;
        int y1v = 1152 - 2 * S[oo][1] - ci;
        int y2v = 1152 - 2 * S[oo][2] - ci;
        int y3v = 1152 - 2 * S[oo][3] - c3;
        size_t idx = obase + (size_t)oo * HW;
        if (RESID) {
            float4 rv4 = *reinterpret_cast<const float4*>(resid + idx);
            float4 tv;
            tv.x = (float)y0 + rv4.x;
            tv.y = (float)y1v + rv4.y;
            tv.z = (float)y2v + rv4.z;
            tv.w = (float)y3v + rv4.w;
            *reinterpret_cast<float4*>(tout + idx) = tv;
            double s = (double)tv.x + (double)tv.y + (double)tv.z + (double)tv.w;
            double ss = (double)tv.x * tv.x + (double)tv.y * tv.y +
                        (double)tv.z * tv.z + (double)tv.w * tv.w;
#pragma unroll
            for (int d = 1; d < 64; d <<= 1) { s += __shfl_xor(s, d); ss += __shfl_xor(ss, d); }
            if (lane == 0) { sW[wid][oo] = s; ssW[wid][oo] = ss; }
        } else {
            short4 sv;
            sv.x = (short)y0; sv.y = (short)y1v; sv.z = (short)y2v; sv.w = (short)y3v;
            *reinterpret_cast<short4*>(yout + idx) = sv;
            int s = y0 + y1v + y2v + y3v;
            int ss = y0 * y0 + y1v * y1v + y2v * y2v + y3v * y3v;
#pragma unroll
            for (int d = 1; d < 64; d <<= 1) { s += __shfl_xor(s, d); ss += __shfl_xor(ss, d); }
            if (lane == 0) { iW[wid][oo] = s; iiW[wid][oo] = ss; }
        }
    }
    __syncthreads();
    if (tid < 8) {
        if (RESID) {
            double s = sW[0][tid] + sW[1][tid] + sW[2][tid] + sW[3][tid];
            double ss = ssW[0][tid] + ssW[1][tid] + ssW[2][tid] + ssW[3][tid];
            atomicAdd(&dsums[o0 + tid], s);
            atomicAdd(&dsums[128 + o0 + tid], ss);
        } else {
            long long s = iW[0][tid] + iW[1][tid] + iW[2][tid] + iW[3][tid];
            long long ss = iiW[0][tid] + iiW[1][tid] + iiW[2][tid] + iiW[3][tid];
            atomicAdd(&isums[o0 + tid], (unsigned long long)s);
            atomicAdd(&isums[128 + o0 + tid], (unsigned long long)ss);
        }
    }
}

// ---------------- K3: threshold y1 through BN1 sign and repack bits for conv2 (2 px/thread)
__global__ void k_pack2(const short* __restrict__ y1,
                        const unsigned long long* __restrict__ sums1,
                        const float* __restrict__ gamma1, const float* __restrict__ beta1,
                        U2* __restrict__ xb2) {
    __shared__ int SG[128], TA[128];
    int tid = threadIdx.x;
    if (tid < 128) {
        long long S = (long long)sums1[tid];
        long long SS = (long long)sums1[128 + tid];
        double N = (double)NPIX;
        double mean = (double)S / N;
        double var = (double)SS / N - mean * mean;
        double rr = 1.0 / sqrt(var + EPSV);
        double s = (double)gamma1[tid] * rr;
        double bb = (double)beta1[tid] - mean * s;
        int sg, A;
        if (s > 0.0) {        // bit = y > T  <=>  y > floor(T)
            double f = floor(-bb / s);
            sg = 1; A = (int)fmax(-2000.0, fmin(2000.0, f));
        } else if (s < 0.0) { // bit = y < T  <=>  -y > -ceil(T)
            double cl = ceil(-bb / s);
            sg = -1; A = -(int)fmax(-2000.0, fmin(2000.0, cl));
        } else {
            sg = 0; A = (bb > 0.0) ? -1 : 0;
        }
        SG[tid] = sg; TA[tid] = A;
    }
    __syncthreads();
    int p2 = blockIdx.x * 256 + tid;   // 2-pixel group
    int pix0 = p2 * 2;
    int b = pix0 / HW, r = pix0 % HW;
    const short* yp = y1 + (size_t)b * CC * HW + r;
    unsigned long long lo0 = 0, hi0 = 0, lo1 = 0, hi1 = 0;
#pragma unroll 8
    for (int o = 0; o < 128; ++o) {
        int v = *reinterpret_cast<const int*>(yp + (size_t)o * HW);
        int ya = (int)(short)(v & 0xffff);
        int yb = v >> 16;
        int sg = SG[o], A = TA[o];
        unsigned long long ba = (unsigned long long)(ya * sg > A);
        unsigned long long bb = (unsigned long long)(yb * sg > A);
        if (o < 64) { lo0 |= ba << o;        lo1 |= bb << o; }
        else        { hi0 |= ba << (o - 64); hi1 |= bb << (o - 64); }
    }
    U2 u;
    u.lo = lo0; u.hi = hi0; xb2[pix0] = u;
    u.lo = lo1; u.hi = hi1; xb2[pix0 + 1] = u;
}

// ---------------- K5: BN2 + hardtanh, in-place on d_out (float4)
__global__ void k_bn2(float* __restrict__ t, const double* __restrict__ sums2,
                      const float* __restrict__ gamma2, const float* __restrict__ beta2) {
    __shared__ float sA[128], bA[128];
    int tid = threadIdx.x;
    if (tid < 128) {
        double N = (double)NPIX;
        double mean = sums2[tid] / N;
        double var = sums2[128 + tid] / N - mean * mean;
        double rr = 1.0 / sqrt(var + EPSV);
        double s = (double)gamma2[tid] * rr;
        double bb = (double)beta2[tid] - mean * s;
        sA[tid] = (float)s; bA[tid] = (float)bb;
    }
    __syncthreads();
    size_t i4 = ((size_t)blockIdx.x * 256 + tid) * 4;
    int c = (int)((i4 / HW) & 127);
    float4 v = *reinterpret_cast<float4*>(t + i4);
    float s = sA[c], bb = bA[c];
    v.x = fminf(1.f, fmaxf(-1.f, v.x * s + bb));
    v.y = fminf(1.f, fmaxf(-1.f, v.y * s + bb));
    v.z = fminf(1.f, fmaxf(-1.f, v.z * s + bb));
    v.w = fminf(1.f, fmaxf(-1.f, v.w * s + bb));
    *reinterpret_cast<float4*>(t + i4) = v;
}

extern "C" void kernel_launch(void* const* d_in, const int* in_sizes, int n_in,
                              void* d_out, int out_size, void* d_ws, size_t ws_size,
                              hipStream_t stream) {
    const float* x      = (const float*)d_in[0];
    const float* w1     = (const float*)d_in[1];
    const float* w2     = (const float*)d_in[2];
    const float* gamma1 = (const float*)d_in[3];
    const float* beta1  = (const float*)d_in[4];
    const float* gamma2 = (const float*)d_in[5];
    const float* beta2  = (const float*)d_in[6];
    float* out = (float*)d_out;

    char* ws = (char*)d_ws;
    U2* wbT1 = (U2*)ws;                ws += 1152 * sizeof(U2);
    U2* wbT2 = (U2*)ws;                ws += 1152 * sizeof(U2);
    int* wpcg = (int*)ws;              ws += 2304 * sizeof(int);
    int* ctab1 = (int*)ws;             ws += 1152 * sizeof(int);
    int* ctab2 = (int*)ws;             ws += 1152 * sizeof(int);
    U2* xb  = (U2*)ws;                 ws += (size_t)NPIX * sizeof(U2);
    U2* xb2 = (U2*)ws;                 ws += (size_t)NPIX * sizeof(U2);
    short* y1 = (short*)ws;            ws += (size_t)NTOT * sizeof(short);
    unsigned long long* sums1 = (unsigned long long*)ws; ws += 256 * sizeof(unsigned long long);
    double* sums2 = (double*)ws;       ws += 256 * sizeof(double);

    k_pack_w<<<9, 256, 0, stream>>>(w1, w2, wbT1, wbT2, wpcg, sums1, sums2);
    k_corr<<<9, 256, 0, stream>>>(wpcg, ctab1, ctab2);
    k_pack_x<<<1568, 256, 0, stream>>>(x, xb);
    k_conv8<0><<<dim3(98, 16), 256, 0, stream>>>(xb, wbT1, ctab1, y1, nullptr, nullptr, sums1, sums2);
    k_pack2<<<196, 256, 0, stream>>>(y1, sums1, gamma1, beta1, xb2);
    k_conv8<1><<<dim3(98, 16), 256, 0, stream>>>(xb2, wbT2, ctab2, nullptr, x, out, sums1, sums2);
    k_bn2<<<12544, 256, 0, stream>>>(out, sums2, gamma2, beta2);
}

// Round 6
// 182.959 us; speedup vs baseline: 1.2144x; 1.2144x over previous
//
#include <hip/hip_runtime.h>
#include <stdint.h>

#define HH 56
#define WW 56
#define HW 3136
#define CC 128
#define BB 32
#define NPIX 100352        // B*H*W
#define NTOT 12845056      // B*C*H*W
#define EPSV 1e-5
#define PR 58              // padded rows
#define PC 64              // padded cols (stride)
#define PIMG (PR * PC)     // 3712 cells per image

struct alignas(16) U2 { unsigned long long lo, hi; };

// ---------------- K0: pack weights (sign bits along input channel) in TAP-MAJOR
// layout wbT[tap*128 + o]; per-(tensor,o,tap) popcount stat; zero accumulators.
__global__ void k_pack_w(const float* __restrict__ w1, const float* __restrict__ w2,
                         U2* __restrict__ wbT1, U2* __restrict__ wbT2,
                         int* __restrict__ wpcg,
                         unsigned long long* __restrict__ sums1,
                         double* __restrict__ sums2) {
    int gtid = blockIdx.x * 256 + threadIdx.x;      // 2304 jobs
    if (gtid < 256) sums1[gtid] = 0ull;
    else if (gtid < 512) sums2[gtid - 256] = 0.0;
    int tensor = gtid / 1152, rem = gtid % 1152;
    int o = rem / 9, tap = rem % 9;
    const float* w = tensor ? w2 : w1;
    unsigned long long lo = 0, hi = 0;
    for (int i = 0; i < 64; ++i)
        if (w[(o * 128 + i) * 9 + tap] > 0.f) lo |= 1ull << i;
    for (int i = 64; i < 128; ++i)
        if (w[(o * 128 + i) * 9 + tap] > 0.f) hi |= 1ull << (i - 64);
    U2 u; u.lo = lo; u.hi = hi;
    (tensor ? wbT2 : wbT1)[tap * 128 + o] = u;
    wpcg[gtid] = 128 - 2 * (int)(__popcll(lo) + __popcll(hi));
}

// ---------------- K0b: border-correction tables ctab[o*9 + pattern] (pattern 0 -> 0)
__global__ void k_corr(const int* __restrict__ wpcg,
                       int* __restrict__ ctab1, int* __restrict__ ctab2) {
    int gtid = blockIdx.x * 256 + threadIdx.x;      // 2304 jobs
    int tensor = gtid / 1152, rem = gtid % 1152;
    int o = rem / 9, p = rem % 9;
    int ph = p / 3, pw = p % 3;
    int c = 0;
#pragma unroll
    for (int t = 0; t < 9; ++t) {
        int kh = t / 3, kw = t % 3;
        bool inval = (ph == 1 && kh == 0) || (ph == 2 && kh == 2) ||
                     (pw == 1 && kw == 0) || (pw == 2 && kw == 2);
        if (inval) c += wpcg[tensor * 1152 + o * 9 + t];
    }
    (tensor ? ctab2 : ctab1)[o * 9 + p] = c;
}

// ---------------- K0c: zero both padded bit-images (borders must be 0)
__global__ void k_zero(U2* __restrict__ xbp1, U2* __restrict__ xbp2) {
    int i = blockIdx.x * 256 + threadIdx.x;         // 2 * 32 * 3712 = 237568 jobs
    U2 z; z.lo = 0ull; z.hi = 0ull;
    if (i < BB * PIMG) xbp1[i] = z;
    else               xbp2[i - BB * PIMG] = z;
}

// ---------------- K1: pack x sign bits into padded layout, coalesced reads.
__global__ void k_pack_x(const float* __restrict__ x, U2* __restrict__ xbp) {
    __shared__ unsigned sm[64][5];                  // +1 pad: conflict-free
    int tid = threadIdx.x;
    int cq = tid >> 6, pl = tid & 63;
    int P0 = blockIdx.x * 64;                       // 64 | HW so b uniform per block
    int pix = P0 + pl;
    int b = pix / HW, r = pix % HW;
    const float* base = x + ((size_t)(b * CC + cq * 32)) * HW + r;
    unsigned m = 0;
#pragma unroll
    for (int c = 0; c < 32; ++c)
        if (base[(size_t)c * HW] > 0.f) m |= 1u << c;
    sm[pl][cq] = m;
    __syncthreads();
    if (tid < 64) {
        int pix2 = P0 + tid;
        int b2 = pix2 / HW, r2 = pix2 % HW;
        int h = r2 / WW, w = r2 % WW;
        U2 u;
        u.lo = (unsigned long long)sm[tid][0] | ((unsigned long long)sm[tid][1] << 32);
        u.hi = (unsigned long long)sm[tid][2] | ((unsigned long long)sm[tid][3] << 32);
        xbp[(size_t)b2 * PIMG + (h + 1) * PC + (w + 1)] = u;
    }
}

// ---------------- K2/K4: binary conv 3x3, 1 px/thread, 8 o-channels/block.
// Padded image -> 9 unconditional dwordx4 loads (one base, imm offsets).
// Weights via scalar path (uniform address). No fused stats.
template <int RESID>
__global__ __launch_bounds__(256)
void k_conv(const U2* __restrict__ xbp, const U2* __restrict__ wbT,
            const int* __restrict__ ctab,
            short* __restrict__ yout,
            const float* __restrict__ resid, float* __restrict__ tout) {
    __shared__ int ct[72];
    int tid = threadIdx.x;
    int o0 = blockIdx.y * 8;
    if (tid < 72) ct[tid] = ctab[o0 * 9 + tid];
    __syncthreads();

    int pix = blockIdx.x * 256 + tid;               // NPIX = 392*256 exact
    int b = pix / HW, r = pix % HW;
    int h = r / WW, w = r % WW;
    const U2* base = xbp + (size_t)b * PIMG + h * PC + w;   // top-left of halo

    int S[8];
#pragma unroll
    for (int oo = 0; oo < 8; ++oo) S[oo] = 0;

#pragma unroll
    for (int t = 0; t < 9; ++t) {
        int kh = t / 3, kw = t % 3;
        uint4 A = *reinterpret_cast<const uint4*>(base + kh * PC + kw);
        const uint4* wq = reinterpret_cast<const uint4*>(wbT + (size_t)t * 128 + o0);
#pragma unroll
        for (int oo = 0; oo < 8; ++oo) {
            uint4 wv = wq[oo];                      // uniform -> s_load
            S[oo] += __popc(A.x ^ wv.x) + __popc(A.y ^ wv.y)
                   + __popc(A.z ^ wv.z) + __popc(A.w ^ wv.w);
        }
    }

    int ph = (h == 0) ? 1 : ((h == HH - 1) ? 2 : 0);
    int pw = (w == 0) ? 1 : ((w == WW - 1) ? 2 : 0);
    int p = ph * 3 + pw;                            // 0 for interior, ct[..0]==0

    size_t obase = (size_t)(b * CC + o0) * HW + r;
#pragma unroll
    for (int oo = 0; oo < 8; ++oo) {
        int y = 1152 - 2 * S[oo] - ct[oo * 9 + p];
        size_t idx = obase + (size_t)oo * HW;
        if (RESID) tout[idx] = (float)y + resid[idx];
        else       yout[idx] = (short)y;
    }
}

// ---------------- K3: exact int sums of y1 per channel (one block per (b,c) plane)
__global__ void k_stats_y1(const short* __restrict__ y1,
                           unsigned long long* __restrict__ isums) {
    int plane = blockIdx.x;                         // b*128 + o
    int o = plane & 127;
    const uint4* p = reinterpret_cast<const uint4*>(y1 + (size_t)plane * HW); // 392 vec
    int s = 0, ss = 0;
    for (int i = threadIdx.x; i < 392; i += 256) {
        uint4 v = p[i];
#pragma unroll
        for (int j = 0; j < 4; ++j) {
            unsigned u = (&v.x)[j];
            int a = (int)(short)(u & 0xffffu);
            int bq = (int)(short)(u >> 16);
            s += a + bq; ss += a * a + bq * bq;
        }
    }
#pragma unroll
    for (int d = 1; d < 64; d <<= 1) { s += __shfl_xor(s, d); ss += __shfl_xor(ss, d); }
    __shared__ long long Ls[4], Lss[4];
    int wid = threadIdx.x >> 6, lane = threadIdx.x & 63;
    if (lane == 0) { Ls[wid] = s; Lss[wid] = ss; }
    __syncthreads();
    if (threadIdx.x == 0) {
        long long S = Ls[0] + Ls[1] + Ls[2] + Ls[3];
        long long SS = Lss[0] + Lss[1] + Lss[2] + Lss[3];
        atomicAdd(&isums[o], (unsigned long long)S);
        atomicAdd(&isums[128 + o], (unsigned long long)SS);
    }
}

// ---------------- K3b: double sums of t per channel (one block per (b,c) plane)
__global__ void k_stats_t(const float* __restrict__ t, double* __restrict__ dsums) {
    int plane = blockIdx.x;
    int o = plane & 127;
    const float4* p = reinterpret_cast<const float4*>(t + (size_t)plane * HW); // 784 vec
    double s = 0.0, ss = 0.0;
    for (int i = threadIdx.x; i < 784; i += 256) {
        float4 v = p[i];
        s += (double)v.x + (double)v.y + (double)v.z + (double)v.w;
        ss += (double)v.x * v.x + (double)v.y * v.y
            + (double)v.z * v.z + (double)v.w * v.w;
    }
#pragma unroll
    for (int d = 1; d < 64; d <<= 1) { s += __shfl_xor(s, d); ss += __shfl_xor(ss, d); }
    __shared__ double Ls[4], Lss[4];
    int wid = threadIdx.x >> 6, lane = threadIdx.x & 63;
    if (lane == 0) { Ls[wid] = s; Lss[wid] = ss; }
    __syncthreads();
    if (threadIdx.x == 0) {
        atomicAdd(&dsums[o], Ls[0] + Ls[1] + Ls[2] + Ls[3]);
        atomicAdd(&dsums[128 + o], Lss[0] + Lss[1] + Lss[2] + Lss[3]);
    }
}

// ---------------- K5: threshold y1 through BN1 sign, repack padded bits for conv2
__global__ void k_pack2(const short* __restrict__ y1,
                        const unsigned long long* __restrict__ sums1,
                        const float* __restrict__ gamma1, const float* __restrict__ beta1,
                        U2* __restrict__ xbp2) {
    __shared__ int SG[128], TA[128];
    int tid = threadIdx.x;
    if (tid < 128) {
        long long S = (long long)sums1[tid];
        long long SS = (long long)sums1[128 + tid];
        double N = (double)NPIX;
        double mean = (double)S / N;
        double var = (double)SS / N - mean * mean;
        double rr = 1.0 / sqrt(var + EPSV);
        double s = (double)gamma1[tid] * rr;
        double bb = (double)beta1[tid] - mean * s;
        int sg, A;
        if (s > 0.0) {        // bit = y > T  <=>  y > floor(T)
            double f = floor(-bb / s);
            sg = 1; A = (int)fmax(-2000.0, fmin(2000.0, f));
        } else if (s < 0.0) { // bit = y < T  <=>  -y > -ceil(T)
            double cl = ceil(-bb / s);
            sg = -1; A = -(int)fmax(-2000.0, fmin(2000.0, cl));
        } else {
            sg = 0; A = (bb > 0.0) ? -1 : 0;
        }
        SG[tid] = sg; TA[tid] = A;
    }
    __syncthreads();
    int p2 = blockIdx.x * 256 + tid;   // 2-pixel group (never crosses a row: WW even)
    int pix0 = p2 * 2;
    int b = pix0 / HW, r = pix0 % HW;
    const short* yp = y1 + (size_t)b * CC * HW + r;
    unsigned long long lo0 = 0, hi0 = 0, lo1 = 0, hi1 = 0;
#pragma unroll 8
    for (int o = 0; o < 128; ++o) {
        int v = *reinterpret_cast<const int*>(yp + (size_t)o * HW);
        int ya = (int)(short)(v & 0xffff);
        int yb = v >> 16;
        int sg = SG[o], A = TA[o];
        unsigned long long ba = (unsigned long long)(ya * sg > A);
        unsigned long long bb = (unsigned long long)(yb * sg > A);
        if (o < 64) { lo0 |= ba << o;        lo1 |= bb << o; }
        else        { hi0 |= ba << (o - 64); hi1 |= bb << (o - 64); }
    }
    int h = r / WW, w = r % WW;
    U2* dst = xbp2 + (size_t)b * PIMG + (h + 1) * PC + (w + 1);
    U2 u;
    u.lo = lo0; u.hi = hi0; dst[0] = u;
    u.lo = lo1; u.hi = hi1; dst[1] = u;
}

// ---------------- K6: BN2 + hardtanh, in-place on d_out (float4)
__global__ void k_bn2(float* __restrict__ t, const double* __restrict__ sums2,
                      const float* __restrict__ gamma2, const float* __restrict__ beta2) {
    __shared__ float sA[128], bA[128];
    int tid = threadIdx.x;
    if (tid < 128) {
        double N = (double)NPIX;
        double mean = sums2[tid] / N;
        double var = sums2[128 + tid] / N - mean * mean;
        double rr = 1.0 / sqrt(var + EPSV);
        double s = (double)gamma2[tid] * rr;
        double bb = (double)beta2[tid] - mean * s;
        sA[tid] = (float)s; bA[tid] = (float)bb;
    }
    __syncthreads();
    size_t i4 = ((size_t)blockIdx.x * 256 + tid) * 4;
    int c = (int)((i4 / HW) & 127);
    float4 v = *reinterpret_cast<float4*>(t + i4);
    float s = sA[c], bb = bA[c];
    v.x = fminf(1.f, fmaxf(-1.f, v.x * s + bb));
    v.y = fminf(1.f, fmaxf(-1.f, v.y * s + bb));
    v.z = fminf(1.f, fmaxf(-1.f, v.z * s + bb));
    v.w = fminf(1.f, fmaxf(-1.f, v.w * s + bb));
    *reinterpret_cast<float4*>(t + i4) = v;
}

extern "C" void kernel_launch(void* const* d_in, const int* in_sizes, int n_in,
                              void* d_out, int out_size, void* d_ws, size_t ws_size,
                              hipStream_t stream) {
    const float* x      = (const float*)d_in[0];
    const float* w1     = (const float*)d_in[1];
    const float* w2     = (const float*)d_in[2];
    const float* gamma1 = (const float*)d_in[3];
    const float* beta1  = (const float*)d_in[4];
    const float* gamma2 = (const float*)d_in[5];
    const float* beta2  = (const float*)d_in[6];
    float* out = (float*)d_out;

    char* ws = (char*)d_ws;
    U2* wbT1 = (U2*)ws;                ws += 1152 * sizeof(U2);
    U2* wbT2 = (U2*)ws;                ws += 1152 * sizeof(U2);
    int* wpcg = (int*)ws;              ws += 2304 * sizeof(int);
    int* ctab1 = (int*)ws;             ws += 1152 * sizeof(int);
    int* ctab2 = (int*)ws;             ws += 1152 * sizeof(int);
    U2* xbp1 = (U2*)ws;                ws += (size_t)BB * PIMG * sizeof(U2);  // 1.9 MB
    U2* xbp2 = (U2*)ws;                ws += (size_t)BB * PIMG * sizeof(U2);  // 1.9 MB
    short* y1 = (short*)ws;            ws += (size_t)NTOT * sizeof(short);    // 25.7 MB
    unsigned long long* sums1 = (unsigned long long*)ws; ws += 256 * sizeof(unsigned long long);
    double* sums2 = (double*)ws;       ws += 256 * sizeof(double);

    k_pack_w<<<9, 256, 0, stream>>>(w1, w2, wbT1, wbT2, wpcg, sums1, sums2);
    k_corr<<<9, 256, 0, stream>>>(wpcg, ctab1, ctab2);
    k_zero<<<928, 256, 0, stream>>>(xbp1, xbp2);
    k_pack_x<<<1568, 256, 0, stream>>>(x, xbp1);
    k_conv<0><<<dim3(392, 16), 256, 0, stream>>>(xbp1, wbT1, ctab1, y1, nullptr, nullptr);
    k_stats_y1<<<4096, 256, 0, stream>>>(y1, sums1);
    k_pack2<<<196, 256, 0, stream>>>(y1, sums1, gamma1, beta1, xbp2);
    k_conv<1><<<dim3(392, 16), 256, 0, stream>>>(xbp2, wbT2, ctab2, nullptr, x, out);
    k_stats_t<<<4096, 256, 0, stream>>>(out, sums2);
    k_bn2<<<12544, 256, 0, stream>>>(out, sums2, gamma2, beta2);
}

// Round 7
// 143.626 us; speedup vs baseline: 1.5470x; 1.2739x over previous
//
#include <hip/hip_runtime.h>
#include <stdint.h>

#define HH 56
#define WW 56
#define HW 3136
#define CC 128
#define BB 32
#define NPIX 100352        // B*H*W
#define NTOT 12845056      // B*C*H*W
#define EPSV 1e-5
#define PR 58              // padded rows
#define PC 64              // padded cols (stride)
#define PIMG (PR * PC)     // 3712 cells per image

struct alignas(16) U2 { unsigned long long lo, hi; };

// ---------------- K0: pack weights (sign bits along input channel), O-MAJOR
// layout wb[o*9 + tap]; per-(tensor,o,tap) popcount stat; zero accumulators.
__global__ void k_pack_w(const float* __restrict__ w1, const float* __restrict__ w2,
                         U2* __restrict__ wb1, U2* __restrict__ wb2,
                         int* __restrict__ wpcg,
                         unsigned long long* __restrict__ sums1,
                         double* __restrict__ sums2) {
    int gtid = blockIdx.x * 256 + threadIdx.x;      // 2304 jobs
    if (gtid < 256) sums1[gtid] = 0ull;
    else if (gtid < 512) sums2[gtid - 256] = 0.0;
    int tensor = gtid / 1152, rem = gtid % 1152;
    int o = rem / 9, tap = rem % 9;
    const float* w = tensor ? w2 : w1;
    unsigned long long lo = 0, hi = 0;
    for (int i = 0; i < 64; ++i)
        if (w[(o * 128 + i) * 9 + tap] > 0.f) lo |= 1ull << i;
    for (int i = 64; i < 128; ++i)
        if (w[(o * 128 + i) * 9 + tap] > 0.f) hi |= 1ull << (i - 64);
    U2 u; u.lo = lo; u.hi = hi;
    (tensor ? wb2 : wb1)[o * 9 + tap] = u;
    wpcg[gtid] = 128 - 2 * (int)(__popcll(lo) + __popcll(hi));
}

// ---------------- K0b: border-correction tables ctab[o*9 + pattern] (pattern 0 -> 0)
__global__ void k_corr(const int* __restrict__ wpcg,
                       int* __restrict__ ctab1, int* __restrict__ ctab2) {
    int gtid = blockIdx.x * 256 + threadIdx.x;      // 2304 jobs
    int tensor = gtid / 1152, rem = gtid % 1152;
    int o = rem / 9, p = rem % 9;
    int ph = p / 3, pw = p % 3;
    int c = 0;
#pragma unroll
    for (int t = 0; t < 9; ++t) {
        int kh = t / 3, kw = t % 3;
        bool inval = (ph == 1 && kh == 0) || (ph == 2 && kh == 2) ||
                     (pw == 1 && kw == 0) || (pw == 2 && kw == 2);
        if (inval) c += wpcg[tensor * 1152 + o * 9 + t];
    }
    (tensor ? ctab2 : ctab1)[o * 9 + p] = c;
}

// ---------------- K0c: zero both padded bit-images (borders must be 0)
__global__ void k_zero(U2* __restrict__ xbp1, U2* __restrict__ xbp2) {
    int i = blockIdx.x * 256 + threadIdx.x;         // 2 * 32 * 3712 = 237568 jobs
    U2 z; z.lo = 0ull; z.hi = 0ull;
    if (i < BB * PIMG) xbp1[i] = z;
    else               xbp2[i - BB * PIMG] = z;
}

// ---------------- K1: pack x sign bits into padded layout, coalesced reads.
__global__ void k_pack_x(const float* __restrict__ x, U2* __restrict__ xbp) {
    __shared__ unsigned sm[64][5];                  // +1 pad: conflict-free
    int tid = threadIdx.x;
    int cq = tid >> 6, pl = tid & 63;
    int P0 = blockIdx.x * 64;                       // 64 | HW so b uniform per block
    int pix = P0 + pl;
    int b = pix / HW, r = pix % HW;
    const float* base = x + ((size_t)(b * CC + cq * 32)) * HW + r;
    unsigned m = 0;
#pragma unroll
    for (int c = 0; c < 32; ++c)
        if (base[(size_t)c * HW] > 0.f) m |= 1u << c;
    sm[pl][cq] = m;
    __syncthreads();
    if (tid < 64) {
        int pix2 = P0 + tid;
        int b2 = pix2 / HW, r2 = pix2 % HW;
        int h = r2 / WW, w = r2 % WW;
        U2 u;
        u.lo = (unsigned long long)sm[tid][0] | ((unsigned long long)sm[tid][1] << 32);
        u.hi = (unsigned long long)sm[tid][2] | ((unsigned long long)sm[tid][3] << 32);
        xbp[(size_t)b2 * PIMG + (h + 1) * PC + (w + 1)] = u;
    }
}

// ---------------- K2/K4: binary conv 3x3, 1 px/thread, 8 o-channels/block.
// OC-OUTER: 9 halo uint4 loaded ONCE into registers (36 VGPR); per oc, 9
// contiguous scalar weight loads (o-major) + 144 VALU popcount ops.
template <int RESID>
__global__ __launch_bounds__(256)
void k_conv(const U2* __restrict__ xbp, const U2* __restrict__ wb,
            const int* __restrict__ ctab,
            short* __restrict__ yout,
            const float* __restrict__ resid, float* __restrict__ tout) {
    __shared__ int ct[72];
    int tid = threadIdx.x;
    int o0 = blockIdx.y * 8;
    if (tid < 72) ct[tid] = ctab[o0 * 9 + tid];
    __syncthreads();

    int pix = blockIdx.x * 256 + tid;               // NPIX = 392*256 exact
    int b = pix / HW, r = pix % HW;
    int h = r / WW, w = r % WW;
    const U2* base = xbp + (size_t)b * PIMG + h * PC + w;   // top-left of halo

    uint4 A[9];
#pragma unroll
    for (int t = 0; t < 9; ++t)
        A[t] = *reinterpret_cast<const uint4*>(base + (t / 3) * PC + (t % 3));

    int ph = (h == 0) ? 1 : ((h == HH - 1) ? 2 : 0);
    int pw = (w == 0) ? 1 : ((w == WW - 1) ? 2 : 0);
    int p = ph * 3 + pw;                            // 0 for interior, ct[..0]==0

    size_t obase = (size_t)(b * CC + o0) * HW + r;
#pragma unroll
    for (int oo = 0; oo < 8; ++oo) {
        const uint4* wq = reinterpret_cast<const uint4*>(wb + (size_t)(o0 + oo) * 9);
        int S = 0;
#pragma unroll
        for (int t = 0; t < 9; ++t) {
            uint4 wv = wq[t];                       // uniform -> s_load, contiguous
            S += __popc(A[t].x ^ wv.x) + __popc(A[t].y ^ wv.y)
               + __popc(A[t].z ^ wv.z) + __popc(A[t].w ^ wv.w);
        }
        int y = 1152 - 2 * S - ct[oo * 9 + p];
        size_t idx = obase + (size_t)oo * HW;
        if (RESID) tout[idx] = (float)y + resid[idx];
        else       yout[idx] = (short)y;
    }
}

// ---------------- K3: exact int sums of y1 per channel (one block per (b,c) plane)
__global__ void k_stats_y1(const short* __restrict__ y1,
                           unsigned long long* __restrict__ isums) {
    int plane = blockIdx.x;                         // b*128 + o
    int o = plane & 127;
    const uint4* p = reinterpret_cast<const uint4*>(y1 + (size_t)plane * HW); // 392 vec
    int s = 0, ss = 0;
    for (int i = threadIdx.x; i < 392; i += 256) {
        uint4 v = p[i];
#pragma unroll
        for (int j = 0; j < 4; ++j) {
            unsigned u = (&v.x)[j];
            int a = (int)(short)(u & 0xffffu);
            int bq = (int)(short)(u >> 16);
            s += a + bq; ss += a * a + bq * bq;
        }
    }
#pragma unroll
    for (int d = 1; d < 64; d <<= 1) { s += __shfl_xor(s, d); ss += __shfl_xor(ss, d); }
    __shared__ long long Ls[4], Lss[4];
    int wid = threadIdx.x >> 6, lane = threadIdx.x & 63;
    if (lane == 0) { Ls[wid] = s; Lss[wid] = ss; }
    __syncthreads();
    if (threadIdx.x == 0) {
        long long S = Ls[0] + Ls[1] + Ls[2] + Ls[3];
        long long SS = Lss[0] + Lss[1] + Lss[2] + Lss[3];
        atomicAdd(&isums[o], (unsigned long long)S);
        atomicAdd(&isums[128 + o], (unsigned long long)SS);
    }
}

// ---------------- K3b: double sums of t per channel (one block per (b,c) plane)
__global__ void k_stats_t(const float* __restrict__ t, double* __restrict__ dsums) {
    int plane = blockIdx.x;
    int o = plane & 127;
    const float4* p = reinterpret_cast<const float4*>(t + (size_t)plane * HW); // 784 vec
    double s = 0.0, ss = 0.0;
    for (int i = threadIdx.x; i < 784; i += 256) {
        float4 v = p[i];
        s += (double)v.x + (double)v.y + (double)v.z + (double)v.w;
        ss += (double)v.x * v.x + (double)v.y * v.y
            + (double)v.z * v.z + (double)v.w * v.w;
    }
#pragma unroll
    for (int d = 1; d < 64; d <<= 1) { s += __shfl_xor(s, d); ss += __shfl_xor(ss, d); }
    __shared__ double Ls[4], Lss[4];
    int wid = threadIdx.x >> 6, lane = threadIdx.x & 63;
    if (lane == 0) { Ls[wid] = s; Lss[wid] = ss; }
    __syncthreads();
    if (threadIdx.x == 0) {
        atomicAdd(&dsums[o], Ls[0] + Ls[1] + Ls[2] + Ls[3]);
        atomicAdd(&dsums[128 + o], Lss[0] + Lss[1] + Lss[2] + Lss[3]);
    }
}

// ---------------- K5: threshold y1 through BN1 sign, repack padded bits for conv2.
// pack_x-style: thread = (channel-quarter, pixel-lane), coalesced short loads.
__global__ void k_pack2(const short* __restrict__ y1,
                        const unsigned long long* __restrict__ sums1,
                        const float* __restrict__ gamma1, const float* __restrict__ beta1,
                        U2* __restrict__ xbp2) {
    __shared__ int SG[128], TA[128];
    __shared__ unsigned sm[64][5];
    int tid = threadIdx.x;
    if (tid < 128) {
        long long S = (long long)sums1[tid];
        long long SS = (long long)sums1[128 + tid];
        double N = (double)NPIX;
        double mean = (double)S / N;
        double var = (double)SS / N - mean * mean;
        double rr = 1.0 / sqrt(var + EPSV);
        double s = (double)gamma1[tid] * rr;
        double bb = (double)beta1[tid] - mean * s;
        int sg, A;
        if (s > 0.0) {        // bit = y > T  <=>  y > floor(T)
            double f = floor(-bb / s);
            sg = 1; A = (int)fmax(-2000.0, fmin(2000.0, f));
        } else if (s < 0.0) { // bit = y < T  <=>  -y > -ceil(T)
            double cl = ceil(-bb / s);
            sg = -1; A = -(int)fmax(-2000.0, fmin(2000.0, cl));
        } else {
            sg = 0; A = (bb > 0.0) ? -1 : 0;
        }
        SG[tid] = sg; TA[tid] = A;
    }
    __syncthreads();
    int cq = tid >> 6, pl = tid & 63;
    int P0 = blockIdx.x * 64;                       // 64 | HW so b uniform per block
    int pix = P0 + pl;
    int b = pix / HW, r = pix % HW;
    const short* yp = y1 + ((size_t)(b * CC + cq * 32)) * HW + r;
    unsigned m = 0;
#pragma unroll
    for (int c = 0; c < 32; ++c) {
        int y = (int)yp[(size_t)c * HW];
        int o = cq * 32 + c;
        if (y * SG[o] > TA[o]) m |= 1u << c;
    }
    sm[pl][cq] = m;
    __syncthreads();
    if (tid < 64) {
        int pix2 = P0 + tid;
        int b2 = pix2 / HW, r2 = pix2 % HW;
        int h = r2 / WW, w = r2 % WW;
        U2 u;
        u.lo = (unsigned long long)sm[tid][0] | ((unsigned long long)sm[tid][1] << 32);
        u.hi = (unsigned long long)sm[tid][2] | ((unsigned long long)sm[tid][3] << 32);
        xbp2[(size_t)b2 * PIMG + (h + 1) * PC + (w + 1)] = u;
    }
}

// ---------------- K6: BN2 + hardtanh, in-place on d_out (float4)
__global__ void k_bn2(float* __restrict__ t, const double* __restrict__ sums2,
                      const float* __restrict__ gamma2, const float* __restrict__ beta2) {
    __shared__ float sA[128], bA[128];
    int tid = threadIdx.x;
    if (tid < 128) {
        double N = (double)NPIX;
        double mean = sums2[tid] / N;
        double var = sums2[128 + tid] / N - mean * mean;
        double rr = 1.0 / sqrt(var + EPSV);
        double s = (double)gamma2[tid] * rr;
        double bb = (double)beta2[tid] - mean * s;
        sA[tid] = (float)s; bA[tid] = (float)bb;
    }
    __syncthreads();
    size_t i4 = ((size_t)blockIdx.x * 256 + tid) * 4;
    int c = (int)((i4 / HW) & 127);
    float4 v = *reinterpret_cast<float4*>(t + i4);
    float s = sA[c], bb = bA[c];
    v.x = fminf(1.f, fmaxf(-1.f, v.x * s + bb));
    v.y = fminf(1.f, fmaxf(-1.f, v.y * s + bb));
    v.z = fminf(1.f, fmaxf(-1.f, v.z * s + bb));
    v.w = fminf(1.f, fmaxf(-1.f, v.w * s + bb));
    *reinterpret_cast<float4*>(t + i4) = v;
}

extern "C" void kernel_launch(void* const* d_in, const int* in_sizes, int n_in,
                              void* d_out, int out_size, void* d_ws, size_t ws_size,
                              hipStream_t stream) {
    const float* x      = (const float*)d_in[0];
    const float* w1     = (const float*)d_in[1];
    const float* w2     = (const float*)d_in[2];
    const float* gamma1 = (const float*)d_in[3];
    const float* beta1  = (const float*)d_in[4];
    const float* gamma2 = (const float*)d_in[5];
    const float* beta2  = (const float*)d_in[6];
    float* out = (float*)d_out;

    char* ws = (char*)d_ws;
    U2* wb1 = (U2*)ws;                 ws += 1152 * sizeof(U2);
    U2* wb2 = (U2*)ws;                 ws += 1152 * sizeof(U2);
    int* wpcg = (int*)ws;              ws += 2304 * sizeof(int);
    int* ctab1 = (int*)ws;             ws += 1152 * sizeof(int);
    int* ctab2 = (int*)ws;             ws += 1152 * sizeof(int);
    U2* xbp1 = (U2*)ws;                ws += (size_t)BB * PIMG * sizeof(U2);  // 1.9 MB
    U2* xbp2 = (U2*)ws;                ws += (size_t)BB * PIMG * sizeof(U2);  // 1.9 MB
    short* y1 = (short*)ws;            ws += (size_t)NTOT * sizeof(short);    // 25.7 MB
    unsigned long long* sums1 = (unsigned long long*)ws; ws += 256 * sizeof(unsigned long long);
    double* sums2 = (double*)ws;       ws += 256 * sizeof(double);

    k_pack_w<<<9, 256, 0, stream>>>(w1, w2, wb1, wb2, wpcg, sums1, sums2);
    k_corr<<<9, 256, 0, stream>>>(wpcg, ctab1, ctab2);
    k_zero<<<928, 256, 0, stream>>>(xbp1, xbp2);
    k_pack_x<<<1568, 256, 0, stream>>>(x, xbp1);
    k_conv<0><<<dim3(392, 16), 256, 0, stream>>>(xbp1, wb1, ctab1, y1, nullptr, nullptr);
    k_stats_y1<<<4096, 256, 0, stream>>>(y1, sums1);
    k_pack2<<<1568, 256, 0, stream>>>(y1, sums1, gamma1, beta1, xbp2);
    k_conv<1><<<dim3(392, 16), 256, 0, stream>>>(xbp2, wb2, ctab2, nullptr, x, out);
    k_stats_t<<<4096, 256, 0, stream>>>(out, sums2);
    k_bn2<<<12544, 256, 0, stream>>>(out, sums2, gamma2, beta2);
}